// Round 2
// baseline (63221.155 us; speedup 1.0000x reference)
//
#include <hip/hip_runtime.h>

#define T_STEPS 24000
#define DIN 598
#define NU 100     // hidden units
#define NG 400     // 4 * NU gates

// ---------------------------------------------------------------------------
// GEMM with bias: C[M,N] = A[M,K] @ B[K,N] + bias[N]   (fp32, 64x64 tile)
// ---------------------------------------------------------------------------
__global__ __launch_bounds__(256) void gemm_bias_kernel(
    const float* __restrict__ A, const float* __restrict__ B,
    const float* __restrict__ bias, float* __restrict__ C,
    int M, int N, int K)
{
    __shared__ float As[16][65];   // As[k][m], +1 pad
    __shared__ float Bs[16][65];   // Bs[k][n], +1 pad
    const int tid = threadIdx.x;
    const int tx = tid & 15;       // n group 0..15
    const int ty = tid >> 4;       // m group 0..15
    const int bm = blockIdx.y * 64;
    const int bn = blockIdx.x * 64;
    float acc[4][4] = {};

    for (int k0 = 0; k0 < K; k0 += 16) {
        // A tile: 64 rows x 16 k
        #pragma unroll
        for (int p = 0; p < 4; ++p) {
            int e = tid + p * 256;
            int r = e >> 4, cc = e & 15;
            int m = bm + r, k = k0 + cc;
            float v = (m < M && k < K) ? A[(long)m * K + k] : 0.f;
            As[cc][r] = v;
        }
        // B tile: 16 k x 64 cols
        #pragma unroll
        for (int p = 0; p < 4; ++p) {
            int e = tid + p * 256;
            int r = e >> 6, cc = e & 63;
            int k = k0 + r, n = bn + cc;
            float v = (k < K && n < N) ? B[(long)k * N + n] : 0.f;
            Bs[r][cc] = v;
        }
        __syncthreads();
        #pragma unroll
        for (int kk = 0; kk < 16; ++kk) {
            float a[4], b[4];
            #pragma unroll
            for (int i = 0; i < 4; ++i) a[i] = As[kk][ty * 4 + i];
            #pragma unroll
            for (int j = 0; j < 4; ++j) b[j] = Bs[kk][tx * 4 + j];
            #pragma unroll
            for (int i = 0; i < 4; ++i)
                #pragma unroll
                for (int j = 0; j < 4; ++j)
                    acc[i][j] += a[i] * b[j];
        }
        __syncthreads();
    }
    #pragma unroll
    for (int i = 0; i < 4; ++i) {
        int m = bm + ty * 4 + i;
        if (m >= M) continue;
        #pragma unroll
        for (int j = 0; j < 4; ++j) {
            int n = bn + tx * 4 + j;
            if (n < N) C[(long)m * N + n] = acc[i][j] + bias[n];
        }
    }
}

// ---------------------------------------------------------------------------
// Serial LSTM recurrence + fused BN.  One workgroup, 448 threads (7 waves).
// Thread j (<400) holds U[:,j] in 100 VGPRs.  h broadcast via LDS.
// xW (input projections) precomputed; out = BN(h_t) written per step.
// ---------------------------------------------------------------------------
__device__ __forceinline__ float sigmoid_(float x) {
    return 1.f / (1.f + __expf(-x));
}
__device__ __forceinline__ float tanh_(float x) {
    // 1 - 2/(e^{2x}+1): saturates correctly at +/-inf, no inf/inf NaN
    float e = __expf(2.f * x);
    return 1.f - 2.f / (e + 1.f);
}

__global__ __launch_bounds__(448) void lstm_bn_kernel(
    const float* __restrict__ xW,     // [T, 400]
    const float* __restrict__ U,      // [100, 400] row-major
    const float* __restrict__ gamma, const float* __restrict__ beta,
    const float* __restrict__ mean,  const float* __restrict__ var,
    float* __restrict__ out)          // [T, 100]  (BN applied)
{
    __shared__ __align__(16) float h_lds[104];
    __shared__ float zact[NG];
    const int tid = threadIdx.x;

    float u[NU];
    if (tid < NG) {
        #pragma unroll
        for (int k = 0; k < NU; ++k) u[k] = U[k * NG + tid];  // coalesced across tid
    }

    float c = 0.f, bsc = 0.f, bsh = 0.f;
    if (tid < NU) {
        float s = gamma[tid] * rsqrtf(var[tid] + 1e-3f);
        bsc = s;
        bsh = beta[tid] - mean[tid] * s;
        h_lds[tid] = 0.f;
    }
    __syncthreads();

    // depth-2 prefetch of xW rows
    float xw0 = (tid < NG) ? xW[tid] : 0.f;
    float xw1 = (tid < NG) ? xW[NG + tid] : 0.f;

    for (int t = 0; t < T_STEPS; ++t) {
        float z = xw0;
        xw0 = xw1;
        if (tid < NG && t + 2 < T_STEPS) xw1 = xW[(long)(t + 2) * NG + tid];

        if (tid < NG) {
            const float4* h4 = (const float4*)h_lds;  // broadcast reads, conflict-free
            #pragma unroll
            for (int q = 0; q < 25; ++q) {
                float4 hv = h4[q];
                z += u[4 * q + 0] * hv.x;
                z += u[4 * q + 1] * hv.y;
                z += u[4 * q + 2] * hv.z;
                z += u[4 * q + 3] * hv.w;
            }
            // Keras gate order i,f,g,o: g = z[200:300] -> tanh, others sigmoid
            float a = (tid >= 2 * NU && tid < 3 * NU) ? tanh_(z) : sigmoid_(z);
            zact[tid] = a;
        }
        __syncthreads();   // zact visible; all h reads of this step done

        if (tid < NU) {
            float iv = zact[tid];
            float fv = zact[tid + NU];
            float gv = zact[tid + 2 * NU];
            float ov = zact[tid + 3 * NU];
            c = fv * c + iv * gv;
            float h = ov * tanh_(c);
            h_lds[tid] = h;
            out[(long)t * NU + tid] = h * bsc + bsh;   // fused BN
        }
        __syncthreads();   // h update visible before next step's dot
    }
}

// ---------------------------------------------------------------------------
// Dense (100->3) + softmax over last dim.  One thread per timestep row.
// ---------------------------------------------------------------------------
__global__ __launch_bounds__(256) void dense_softmax_kernel(
    const float* __restrict__ H,   // [T, 100]
    const float* __restrict__ Wd,  // [100, 3]
    const float* __restrict__ bd,  // [3]
    float* __restrict__ out,       // [T, 3]
    int T)
{
    __shared__ float w[300];
    __shared__ float b[3];
    const int tid = threadIdx.x;
    // BUGFIX (round 1): blockDim is 256, so a single `if (tid < 300)` left
    // w[256..299] uninitialized -> garbage contribution of h[86..99].
    for (int i = tid; i < 300; i += 256) w[i] = Wd[i];
    if (tid < 3) b[tid] = bd[tid];
    __syncthreads();

    int row = blockIdx.x * blockDim.x + tid;
    if (row >= T) return;
    const float* h = H + (long)row * NU;
    float s0 = b[0], s1 = b[1], s2 = b[2];
    #pragma unroll 4
    for (int k = 0; k < NU; ++k) {
        float hv = h[k];
        s0 += hv * w[3 * k + 0];
        s1 += hv * w[3 * k + 1];
        s2 += hv * w[3 * k + 2];
    }
    float m = fmaxf(s0, fmaxf(s1, s2));
    float e0 = __expf(s0 - m), e1 = __expf(s1 - m), e2 = __expf(s2 - m);
    float inv = 1.f / (e0 + e1 + e2);
    out[(long)row * 3 + 0] = e0 * inv;
    out[(long)row * 3 + 1] = e1 * inv;
    out[(long)row * 3 + 2] = e2 * inv;
}

// ---------------------------------------------------------------------------
extern "C" void kernel_launch(void* const* d_in, const int* in_sizes, int n_in,
                              void* d_out, int out_size, void* d_ws, size_t ws_size,
                              hipStream_t stream)
{
    const float* x   = (const float*)d_in[0];
    const float* W1  = (const float*)d_in[1];
    const float* U1  = (const float*)d_in[2];
    const float* b1  = (const float*)d_in[3];
    const float* ga1 = (const float*)d_in[4];
    const float* be1 = (const float*)d_in[5];
    const float* mu1 = (const float*)d_in[6];
    const float* va1 = (const float*)d_in[7];
    const float* W2  = (const float*)d_in[8];
    const float* U2  = (const float*)d_in[9];
    const float* b2  = (const float*)d_in[10];
    const float* ga2 = (const float*)d_in[11];
    const float* be2 = (const float*)d_in[12];
    const float* mu2 = (const float*)d_in[13];
    const float* va2 = (const float*)d_in[14];
    const float* W3  = (const float*)d_in[15];
    const float* U3  = (const float*)d_in[16];
    const float* b3  = (const float*)d_in[17];
    const float* ga3 = (const float*)d_in[18];
    const float* be3 = (const float*)d_in[19];
    const float* mu3 = (const float*)d_in[20];
    const float* va3 = (const float*)d_in[21];
    const float* Wd  = (const float*)d_in[22];
    const float* bd  = (const float*)d_in[23];

    float* xw = (float*)d_ws;                       // [24000,400]  9.6M floats
    float* h1 = xw + (size_t)T_STEPS * NG;          // [24000,100]  2.4M
    float* h2 = h1 + (size_t)T_STEPS * NU;          // [24000,100]  2.4M
    float* h3 = h1;                                 // reuse h1 (dead after xW2 GEMM)
    float* out = (float*)d_out;

    dim3 blk(256);
    dim3 grd((NG + 63) / 64, (T_STEPS + 63) / 64);  // (7, 375)

    // Layer 1
    gemm_bias_kernel<<<grd, blk, 0, stream>>>(x, W1, b1, xw, T_STEPS, NG, DIN);
    lstm_bn_kernel<<<1, 448, 0, stream>>>(xw, U1, ga1, be1, mu1, va1, h1);
    // Layer 2
    gemm_bias_kernel<<<grd, blk, 0, stream>>>(h1, W2, b2, xw, T_STEPS, NG, NU);
    lstm_bn_kernel<<<1, 448, 0, stream>>>(xw, U2, ga2, be2, mu2, va2, h2);
    // Layer 3
    gemm_bias_kernel<<<grd, blk, 0, stream>>>(h2, W3, b3, xw, T_STEPS, NG, NU);
    lstm_bn_kernel<<<1, 448, 0, stream>>>(xw, U3, ga3, be3, mu3, va3, h3);
    // Dense + softmax
    dense_softmax_kernel<<<(T_STEPS + 255) / 256, 256, 0, stream>>>(h3, Wd, bd, out, T_STEPS);
}